// Round 18
// baseline (114.025 us; speedup 1.0000x reference)
//
#include <hip/hip_runtime.h>

// Problem constants (fixed by the reference)
#define N_NODES   100000
#define N_EDGES   1600000
#define IN_CH     16
#define HID_CH    64
#define OUT_CH    128
#define N_GRAPHS  128

// Capacities. Expected: slots ~2.2K, list1 ~35K, list2 ~2K.
#define CAPS  4096
#define CAP1  65536
#define CAP2  16384

#define BM_WORDS ((N_NODES + 31) / 32)      // 3125 words; snapshot 3136, alloc 3200
#define BM_PAD   3200

#define NBLK   2048                         // 8 blocks/CU x 256 CU
#define SCAN_CHUNK 784                      // 4-aligned; NBLK*784 >= N_EDGES

// LDS arena (ints): [0..3135] bitmap ; lbuf @3136 (784) ; scnt @4000
#define SMEM_INTS 4224
#define LBUF_OFF  3136
#define SCNT_OFF  4000

typedef int      iv4 __attribute__((ext_vector_type(4)));
typedef float    fv4 __attribute__((ext_vector_type(4)));

struct P {
    const float* x; const int* src; const int* dst; const int* ptr;
    const float* W1; const float* b1; const float* W2; const float* b2;
    float* out;
    unsigned* deg; int* map1; int* slotnode; int* list1; int* list2;
    float* agg1;                            // [CAPS][16]: sum of dis_s * x[s]
    unsigned* markbm; unsigned* ndbm; int* cnt;
};

// Snapshot bitmap global->LDS with cached int4 loads (L2-resident).
__device__ __forceinline__ void snap_bm(const unsigned* g, unsigned* lds) {
    for (int t = threadIdx.x; t < 3136 / 4; t += blockDim.x)
        ((iv4*)lds)[t] = ((const iv4*)g)[t];
    __syncthreads();
}

// ---------------- kernels ----------------
// Multi-kernel pipeline: dispatch boundaries provide cross-phase visibility
// (validated R5-R17, absmax 0). Plain cached accesses; atomics only for
// true aggregation (deg, agg1, out, bitmaps, counters).

// Prep (tiny): zero markbm + cnt only. Other init distributed into later
// kernels at their earliest safe point.
__global__ void k_prep(P p) {
    int i = blockIdx.x * blockDim.x + threadIdx.x;
    int st = gridDim.x * blockDim.x;
    iv4 z = {0, 0, 0, 0};
    for (int n = i; n < BM_PAD / 4; n += st) ((iv4*)p.markbm)[n] = z;
    if (i < 16) p.cnt[i] = 0;
}

// Pass 1: LDS central bitmap from ptr; scan chunk; central-dst edges -> list2
// (LDS buffer, one counter atomic per block); srcs + centrals -> markbm.
// Also zeroes deg and ndbm (first used in p3 / np2 — safe here).
__global__ void __launch_bounds__(256) k_p1(P p) {
    __shared__ int smem[SMEM_INTS];
    unsigned* cbm = (unsigned*)smem;
    int* lbuf = smem + LBUF_OFF;
    int* scnt = smem + SCNT_OFF;
    for (int t = threadIdx.x; t < 3136; t += blockDim.x) cbm[t] = 0u;
    if (threadIdx.x == 0) scnt[0] = 0;
    __syncthreads();
    if (threadIdx.x < N_GRAPHS) {
        int c = p.ptr[threadIdx.x];
        atomicOr(&cbm[c >> 5], 1u << (c & 31));
        if (blockIdx.x == 0)
            atomicOr(&p.markbm[c >> 5], 1u << (c & 31));
    }
    // distributed init (buffers untouched by this kernel's logic)
    int gid = blockIdx.x * blockDim.x + threadIdx.x;
    int gst = gridDim.x * blockDim.x;
    iv4 z = {0, 0, 0, 0};
    for (int n = gid; n < N_NODES / 4; n += gst) ((iv4*)p.deg)[n] = z;
    for (int n = gid; n < BM_PAD / 4; n += gst) ((iv4*)p.ndbm)[n] = z;
    __syncthreads();
    if (threadIdx.x < SCAN_CHUNK / 4) {
        int e = blockIdx.x * SCAN_CHUNK + threadIdx.x * 4;
        if (e < N_EDGES) {
            iv4 d4 = *(const iv4*)(p.dst + e);
#pragma unroll
            for (int k = 0; k < 4; ++k) {
                int d = d4[k];
                if ((cbm[d >> 5] >> (d & 31)) & 1u) {
                    int s = p.src[e + k];
                    atomicOr(&p.markbm[s >> 5], 1u << (s & 31));
                    lbuf[atomicAdd(&scnt[0], 1)] = e + k;
                }
            }
        }
    }
    __syncthreads();
    if (threadIdx.x == 0) scnt[1] = atomicAdd(&p.cnt[2], scnt[0]);
    __syncthreads();
    for (int t = threadIdx.x; t < scnt[0]; t += blockDim.x) {
        int gi = scnt[1] + t;
        if (gi < CAP2) p.list2[gi] = lbuf[t];
    }
}

// Pass 2 (fused): snapshot markbm; (a) compact marked nodes -> slots
// (wave-aggregated counter; first 13 blocks cover all words); (b) scan:
// marked-dst edges -> list1 (LDS buffer), srcs -> ndbm.
// Also zeroes agg1 and inits out=b2 (first used in l1a / l2 — safe here).
__global__ void __launch_bounds__(256) k_np2(P p) {
    __shared__ int smem[SMEM_INTS];
    unsigned* mbs = (unsigned*)smem;
    int* lbuf = smem + LBUF_OFF;
    int* scnt = smem + SCNT_OFF;
    if (threadIdx.x == 0) scnt[0] = 0;
    snap_bm(p.markbm, mbs);                 // ends with __syncthreads

    // distributed init
    int gid = blockIdx.x * blockDim.x + threadIdx.x;
    int gst = gridDim.x * blockDim.x;
    for (int n = gid; n < (CAPS * IN_CH) / 4; n += gst)
        ((fv4*)p.agg1)[n] = (fv4){0.f, 0.f, 0.f, 0.f};
    for (int n = gid; n < (N_GRAPHS * OUT_CH) / 4; n += gst) {
        int c = (n * 4) & 127;
        ((fv4*)p.out)[n] = (fv4){ p.b2[c], p.b2[c + 1], p.b2[c + 2], p.b2[c + 3] };
    }

    // (a) node compaction
    int gidx = blockIdx.x * blockDim.x + threadIdx.x;
    int lane = threadIdx.x & 63;
    if (blockIdx.x * (int)blockDim.x < BM_WORDS) {
        unsigned w = (gidx < BM_WORDS) ? mbs[gidx] : 0u;
        if (w) atomicOr(&p.ndbm[gidx], w);
        int c = __popc(w);
        int inc = c;
        for (int off = 1; off < 64; off <<= 1) {
            int t = __shfl_up(inc, off, 64);
            if (lane >= off) inc += t;
        }
        int total = __shfl(inc, 63, 64);
        if (total > 0) {
            int base = 0;
            if (lane == 63) base = atomicAdd(&p.cnt[0], total);
            base = __shfl(base, 63, 64);
            int slot = base + inc - c;
            unsigned ww = w;
            while (ww) {
                int b = __ffs(ww) - 1; ww &= ww - 1;
                int n = (gidx << 5) + b;
                if (slot < CAPS) { p.map1[n] = slot; p.slotnode[slot] = n; }
                else               p.map1[n] = 0;   // overflow: clamp, never fault
                ++slot;
            }
        }
    }

    // (b) list1 scan
    if (threadIdx.x < SCAN_CHUNK / 4) {
        int e = blockIdx.x * SCAN_CHUNK + threadIdx.x * 4;
        if (e < N_EDGES) {
            iv4 d4 = *(const iv4*)(p.dst + e);
#pragma unroll
            for (int k = 0; k < 4; ++k) {
                int d = d4[k];
                if ((mbs[d >> 5] >> (d & 31)) & 1u) {
                    int s = p.src[e + k];
                    atomicOr(&p.ndbm[s >> 5], 1u << (s & 31));
                    lbuf[atomicAdd(&scnt[0], 1)] = e + k;
                }
            }
        }
    }
    __syncthreads();
    if (threadIdx.x == 0) scnt[1] = atomicAdd(&p.cnt[1], scnt[0]);
    __syncthreads();
    for (int t = threadIdx.x; t < scnt[0]; t += blockDim.x) {
        int gi = scnt[1] + t;
        if (gi < CAP1) p.list1[gi] = lbuf[t];
    }
}

// Pass 3: snapshot ndbm; degree count only for dst in the needed set (~31%).
__global__ void __launch_bounds__(256) k_p3(P p) {
    __shared__ int smem[SMEM_INTS];
    unsigned* nds = (unsigned*)smem;
    snap_bm(p.ndbm, nds);                   // ends with __syncthreads
    if (threadIdx.x < SCAN_CHUNK / 4) {
        int e = blockIdx.x * SCAN_CHUNK + threadIdx.x * 4;
        if (e < N_EDGES) {
            iv4 d4 = *(const iv4*)(p.dst + e);
#pragma unroll
            for (int k = 0; k < 4; ++k) {
                int d = d4[k];
                if ((nds[d >> 5] >> (d & 31)) & 1u) atomicAdd(&p.deg[d], 1u);
            }
        }
    }
}

// Layer-1 aggregate: per list1 edge, agg1[slot(dst)] += dis[src] * x[src].
// 16-dim aggregation (W1 GEMV deferred to k_l2 — linearity of the conv).
// Wave = 4 edges x 16 channels. 560K atomics vs 2.4M in the message form.
__global__ void __launch_bounds__(256) k_l1a(P p) {
    int lane = threadIdx.x & 63;
    int g = lane >> 4;                      // edge-in-group 0..3
    int c = lane & 15;                      // channel 0..15
    int wid = blockIdx.x * (blockDim.x >> 6) + (threadIdx.x >> 6);
    int nw = gridDim.x * (blockDim.x >> 6);
    int n1 = min(p.cnt[1], CAP1);
    for (int base = wid * 4; base < n1; base += nw * 4) {
        int myE = base + g;
        if (myE < n1) {
            int e = p.list1[myE];           // uniform across 16 lanes: 1 txn
            int s = p.src[e];
            int d = p.dst[e];
            int slot = p.map1[d]; if (slot < 0) slot = 0;
            float w = rsqrtf((float)(1u + p.deg[s]));
            float xv = p.x[(size_t)s * IN_CH + c];
            atomicAdd(&p.agg1[(size_t)slot * IN_CH + c], w * xv);
        }
    }
}

// Layer-2: per item (list2 edge or central self), recompute
// h1relu = relu((dis_s*agg1[slot] + dis_s^2*x[s]) @ W1 + b1) in-register,
// then W2 GEMV; atomics into out (bias pre-set). Ballot row resolution;
// duplicate central rows each accumulate independently.
__global__ void __launch_bounds__(256) k_l2(P p) {
    __shared__ float w1s[IN_CH * HID_CH];   // 4 KB
    __shared__ float b1s[HID_CH];
    __shared__ float w2s[HID_CH * OUT_CH];  // 32 KB
    __shared__ int cent[128];
    for (int t = threadIdx.x; t < IN_CH * HID_CH; t += blockDim.x) w1s[t] = p.W1[t];
    if (threadIdx.x < HID_CH) b1s[threadIdx.x] = p.b1[threadIdx.x];
    for (int t = threadIdx.x; t < HID_CH * OUT_CH; t += blockDim.x) w2s[t] = p.W2[t];
    if (threadIdx.x < 128) cent[threadIdx.x] = p.ptr[threadIdx.x];
    __syncthreads();
    int lane = threadIdx.x & 63;
    int c0 = cent[lane];
    int c1v = cent[lane + 64];
    int wid = blockIdx.x * (blockDim.x >> 6) + (threadIdx.x >> 6);
    int nw = gridDim.x * (blockDim.x >> 6);
    int n2 = min(p.cnt[2], CAP2);
    for (int w = wid; w < n2 + N_GRAPHS; w += nw) {
        int s, d, selfrow = -1;
        if (w < n2) {
            int e = p.list2[w];
            s = p.src[e]; d = p.dst[e];
        } else {
            selfrow = w - n2;
            s = cent[selfrow]; d = s;
        }
        int slot = p.map1[s]; if (slot < 0) slot = 0;  // always marked
        float dis_s = rsqrtf((float)(1u + p.deg[s]));
        float dis_d = rsqrtf((float)(1u + p.deg[d]));
        float norm = dis_s * dis_d;
        // v[c] = dis_s*agg1[slot][c] + dis_s^2*x[s][c]  (lanes 0..15 hold v)
        float vc = 0.0f;
        if (lane < IN_CH)
            vc = dis_s * p.agg1[(size_t)slot * IN_CH + lane]
               + dis_s * dis_s * p.x[(size_t)s * IN_CH + lane];
        // h1relu[lane] = relu(v @ W1[:,lane] + b1[lane])
        float h = b1s[lane];
#pragma unroll
        for (int c = 0; c < IN_CH; ++c)
            h += __shfl(vc, c, 64) * w1s[c * HID_CH + lane];
        h = fmaxf(h, 0.0f);
        // out GEMV: lane covers channels lane and lane+64
        float a0 = 0.0f, a1 = 0.0f;
#pragma unroll 8
        for (int j = 0; j < HID_CH; ++j) {
            float hv = __shfl(h, j, 64);
            a0 += hv * w2s[j * OUT_CH + lane];
            a1 += hv * w2s[j * OUT_CH + lane + 64];
        }
        a0 *= norm; a1 *= norm;
        if (selfrow >= 0) {
            atomicAdd(&p.out[selfrow * OUT_CH + lane], a0);
            atomicAdd(&p.out[selfrow * OUT_CH + lane + 64], a1);
        } else {
            unsigned long long b0 = __ballot(c0 == d);
            unsigned long long b1 = __ballot(c1v == d);
            while (b0) {
                int r = __ffsll((long long)b0) - 1; b0 &= b0 - 1;
                atomicAdd(&p.out[r * OUT_CH + lane], a0);
                atomicAdd(&p.out[r * OUT_CH + lane + 64], a1);
            }
            while (b1) {
                int r = __ffsll((long long)b1) - 1 + 64; b1 &= b1 - 1;
                atomicAdd(&p.out[r * OUT_CH + lane], a0);
                atomicAdd(&p.out[r * OUT_CH + lane + 64], a1);
            }
        }
    }
}

// ---------------- launch ----------------

extern "C" void kernel_launch(void* const* d_in, const int* in_sizes, int n_in,
                              void* d_out, int out_size, void* d_ws, size_t ws_size,
                              hipStream_t stream) {
    P p;
    p.x   = (const float*)d_in[0];          // fp32 (validated)
    const int* edge = (const int*)d_in[1];  // int32 (validated)
    p.src = edge;
    p.dst = edge + N_EDGES;
    p.ptr = (const int*)d_in[2];
    p.W1  = (const float*)d_in[3];
    p.b1  = (const float*)d_in[4];
    p.W2  = (const float*)d_in[5];
    p.b2  = (const float*)d_in[6];
    p.out = (float*)d_out;

    char* q = (char*)d_ws;
    auto alloc = [&](size_t bytes) {
        char* r = q; q += (bytes + 255) & ~size_t(255); return r;
    };
    p.deg      = (unsigned*)alloc((size_t)N_NODES * 4);
    p.map1     = (int*)     alloc((size_t)N_NODES * 4);
    p.slotnode = (int*)     alloc((size_t)CAPS * 4);
    p.list1    = (int*)     alloc((size_t)CAP1 * 4);
    p.list2    = (int*)     alloc((size_t)CAP2 * 4);
    p.agg1     = (float*)   alloc((size_t)CAPS * IN_CH * 4);
    p.markbm   = (unsigned*)alloc((size_t)BM_PAD * 4);
    p.ndbm     = (unsigned*)alloc((size_t)BM_PAD * 4);
    p.cnt      = (int*)     alloc(256);

    hipLaunchKernelGGL(k_prep, dim3(8),    dim3(256), 0, stream, p);
    hipLaunchKernelGGL(k_p1,   dim3(NBLK), dim3(256), 0, stream, p);
    hipLaunchKernelGGL(k_np2,  dim3(NBLK), dim3(256), 0, stream, p);
    hipLaunchKernelGGL(k_p3,   dim3(NBLK), dim3(256), 0, stream, p);
    hipLaunchKernelGGL(k_l1a,  dim3(NBLK), dim3(256), 0, stream, p);
    hipLaunchKernelGGL(k_l2,   dim3(128),  dim3(256), 0, stream, p);
}

// Round 19
// 84.559 us; speedup vs baseline: 1.3485x; 1.3485x over previous
//
#include <hip/hip_runtime.h>

// Problem constants (fixed by the reference)
#define N_NODES   100000
#define N_EDGES   1600000
#define IN_CH     16
#define HID_CH    64
#define OUT_CH    128
#define N_GRAPHS  128

// Capacities. Expected: slots ~2.2K, list1 ~35K, list2 ~2K.
#define CAPS  4096
#define CAP1  65536
#define CAP2  16384

#define BM_WORDS ((N_NODES + 31) / 32)      // 3125 words; snapshot 3136, alloc 3200
#define BM_PAD   3200

// R19 geometry: 4x fewer, 4x fatter blocks (test: dispatch-ramp theory).
#define NBLK   512                          // 2 blocks/CU
#define SCAN_CHUNK 3128                     // 4-aligned; 512*3128 >= N_EDGES
#define SCAN_V   (SCAN_CHUNK / 4)           // 782 int4 vectors per block

// LDS arena (ints): [0..3135] bitmap ; lbuf @3136 (3128) ; scnt @6272
#define SMEM_INTS 6304
#define LBUF_OFF  3136
#define SCNT_OFF  6272

typedef int      iv4 __attribute__((ext_vector_type(4)));
typedef float    fv4 __attribute__((ext_vector_type(4)));

struct P {
    const float* x; const int* src; const int* dst; const int* ptr;
    const float* W1; const float* b1; const float* W2; const float* b2;
    float* out;
    unsigned* deg; int* map1; int* slotnode; int* list1; int* list2;
    float* agg1;                            // [CAPS][16]: sum of dis_s * x[s]
    unsigned* markbm; unsigned* ndbm; int* cnt;
};

// Snapshot bitmap global->LDS with cached int4 loads (L2-resident).
__device__ __forceinline__ void snap_bm(const unsigned* g, unsigned* lds) {
    for (int t = threadIdx.x; t < 3136 / 4; t += blockDim.x)
        ((iv4*)lds)[t] = ((const iv4*)g)[t];
    __syncthreads();
}

// ---------------- kernels ----------------
// Multi-kernel pipeline: dispatch boundaries provide cross-phase visibility
// (validated R5-R18, absmax 0). Plain cached accesses; atomics only for
// true aggregation (deg, agg1, out, bitmaps, counters).

// Prep (tiny): zero markbm + cnt only.
__global__ void k_prep(P p) {
    int i = blockIdx.x * blockDim.x + threadIdx.x;
    int st = gridDim.x * blockDim.x;
    iv4 z = {0, 0, 0, 0};
    for (int n = i; n < BM_PAD / 4; n += st) ((iv4*)p.markbm)[n] = z;
    if (i < 16) p.cnt[i] = 0;
}

// Pass 1: LDS central bitmap from ptr; scan chunk; central-dst edges -> list2
// (LDS buffer, one counter atomic per block); srcs + centrals -> markbm.
// Also zeroes deg and ndbm (first used later — safe here).
__global__ void __launch_bounds__(256) k_p1(P p) {
    __shared__ int smem[SMEM_INTS];
    unsigned* cbm = (unsigned*)smem;
    int* lbuf = smem + LBUF_OFF;
    int* scnt = smem + SCNT_OFF;
    for (int t = threadIdx.x; t < 3136; t += blockDim.x) cbm[t] = 0u;
    if (threadIdx.x == 0) scnt[0] = 0;
    __syncthreads();
    if (threadIdx.x < N_GRAPHS) {
        int c = p.ptr[threadIdx.x];
        atomicOr(&cbm[c >> 5], 1u << (c & 31));
        if (blockIdx.x == 0)
            atomicOr(&p.markbm[c >> 5], 1u << (c & 31));
    }
    // distributed init (buffers untouched by this kernel's logic)
    int gid = blockIdx.x * blockDim.x + threadIdx.x;
    int gst = gridDim.x * blockDim.x;
    iv4 z = {0, 0, 0, 0};
    for (int n = gid; n < N_NODES / 4; n += gst) ((iv4*)p.deg)[n] = z;
    for (int n = gid; n < BM_PAD / 4; n += gst) ((iv4*)p.ndbm)[n] = z;
    __syncthreads();
    int e0 = blockIdx.x * SCAN_CHUNK;
    for (int t = threadIdx.x; t < SCAN_V; t += blockDim.x) {
        int e = e0 + t * 4;
        if (e < N_EDGES) {
            iv4 d4 = *(const iv4*)(p.dst + e);
#pragma unroll
            for (int k = 0; k < 4; ++k) {
                int d = d4[k];
                if ((cbm[d >> 5] >> (d & 31)) & 1u) {
                    int s = p.src[e + k];
                    atomicOr(&p.markbm[s >> 5], 1u << (s & 31));
                    lbuf[atomicAdd(&scnt[0], 1)] = e + k;
                }
            }
        }
    }
    __syncthreads();
    if (threadIdx.x == 0) scnt[1] = atomicAdd(&p.cnt[2], scnt[0]);
    __syncthreads();
    for (int t = threadIdx.x; t < scnt[0]; t += blockDim.x) {
        int gi = scnt[1] + t;
        if (gi < CAP2) p.list2[gi] = lbuf[t];
    }
}

// Pass 2 (fused): snapshot markbm; (a) compact marked nodes -> slots
// (wave-aggregated counter; first 13 blocks cover all words); (b) scan:
// marked-dst edges -> list1 (LDS buffer), srcs -> ndbm.
// Also zeroes agg1 and inits out=b2 (first used later — safe here).
__global__ void __launch_bounds__(256) k_np2(P p) {
    __shared__ int smem[SMEM_INTS];
    unsigned* mbs = (unsigned*)smem;
    int* lbuf = smem + LBUF_OFF;
    int* scnt = smem + SCNT_OFF;
    if (threadIdx.x == 0) scnt[0] = 0;
    snap_bm(p.markbm, mbs);                 // ends with __syncthreads

    // distributed init
    int gid = blockIdx.x * blockDim.x + threadIdx.x;
    int gst = gridDim.x * blockDim.x;
    for (int n = gid; n < (CAPS * IN_CH) / 4; n += gst)
        ((fv4*)p.agg1)[n] = (fv4){0.f, 0.f, 0.f, 0.f};
    for (int n = gid; n < (N_GRAPHS * OUT_CH) / 4; n += gst) {
        int c = (n * 4) & 127;
        ((fv4*)p.out)[n] = (fv4){ p.b2[c], p.b2[c + 1], p.b2[c + 2], p.b2[c + 3] };
    }

    // (a) node compaction
    int gidx = blockIdx.x * blockDim.x + threadIdx.x;
    int lane = threadIdx.x & 63;
    if (blockIdx.x * (int)blockDim.x < BM_WORDS) {
        unsigned w = (gidx < BM_WORDS) ? mbs[gidx] : 0u;
        if (w) atomicOr(&p.ndbm[gidx], w);
        int c = __popc(w);
        int inc = c;
        for (int off = 1; off < 64; off <<= 1) {
            int t = __shfl_up(inc, off, 64);
            if (lane >= off) inc += t;
        }
        int total = __shfl(inc, 63, 64);
        if (total > 0) {
            int base = 0;
            if (lane == 63) base = atomicAdd(&p.cnt[0], total);
            base = __shfl(base, 63, 64);
            int slot = base + inc - c;
            unsigned ww = w;
            while (ww) {
                int b = __ffs(ww) - 1; ww &= ww - 1;
                int n = (gidx << 5) + b;
                if (slot < CAPS) { p.map1[n] = slot; p.slotnode[slot] = n; }
                else               p.map1[n] = 0;   // overflow: clamp, never fault
                ++slot;
            }
        }
    }

    // (b) list1 scan
    int e0 = blockIdx.x * SCAN_CHUNK;
    for (int t = threadIdx.x; t < SCAN_V; t += blockDim.x) {
        int e = e0 + t * 4;
        if (e < N_EDGES) {
            iv4 d4 = *(const iv4*)(p.dst + e);
#pragma unroll
            for (int k = 0; k < 4; ++k) {
                int d = d4[k];
                if ((mbs[d >> 5] >> (d & 31)) & 1u) {
                    int s = p.src[e + k];
                    atomicOr(&p.ndbm[s >> 5], 1u << (s & 31));
                    lbuf[atomicAdd(&scnt[0], 1)] = e + k;
                }
            }
        }
    }
    __syncthreads();
    if (threadIdx.x == 0) scnt[1] = atomicAdd(&p.cnt[1], scnt[0]);
    __syncthreads();
    for (int t = threadIdx.x; t < scnt[0]; t += blockDim.x) {
        int gi = scnt[1] + t;
        if (gi < CAP1) p.list1[gi] = lbuf[t];
    }
}

// Pass 3: snapshot ndbm; degree count only for dst in the needed set (~31%).
__global__ void __launch_bounds__(256) k_p3(P p) {
    __shared__ int smem[SMEM_INTS];
    unsigned* nds = (unsigned*)smem;
    snap_bm(p.ndbm, nds);                   // ends with __syncthreads
    int e0 = blockIdx.x * SCAN_CHUNK;
    for (int t = threadIdx.x; t < SCAN_V; t += blockDim.x) {
        int e = e0 + t * 4;
        if (e < N_EDGES) {
            iv4 d4 = *(const iv4*)(p.dst + e);
#pragma unroll
            for (int k = 0; k < 4; ++k) {
                int d = d4[k];
                if ((nds[d >> 5] >> (d & 31)) & 1u) atomicAdd(&p.deg[d], 1u);
            }
        }
    }
}

// Layer-1 aggregate: per list1 edge, agg1[slot(dst)] += dis[src] * x[src].
// 16-dim aggregation (W1 GEMV deferred to k_l2 — linearity). Wave = 4 edges
// x 16 channels; per-group loads are uniform (single txn + broadcast).
__global__ void __launch_bounds__(256) k_l1a(P p) {
    int lane = threadIdx.x & 63;
    int g = lane >> 4;                      // edge-in-group 0..3
    int c = lane & 15;                      // channel 0..15
    int wid = blockIdx.x * (blockDim.x >> 6) + (threadIdx.x >> 6);
    int nw = gridDim.x * (blockDim.x >> 6);
    int n1 = min(p.cnt[1], CAP1);
    for (int base = wid * 4; base < n1; base += nw * 4) {
        int myE = base + g;
        if (myE < n1) {
            int e = p.list1[myE];
            int s = p.src[e];
            int d = p.dst[e];
            int slot = p.map1[d]; if (slot < 0) slot = 0;
            float w = rsqrtf((float)(1u + p.deg[s]));
            float xv = p.x[(size_t)s * IN_CH + c];
            atomicAdd(&p.agg1[(size_t)slot * IN_CH + c], w * xv);
        }
    }
}

// Layer-2: per item (list2 edge or central self), recompute
// h1relu = relu((dis_s*agg1[slot] + dis_s^2*x[s]) @ W1 + b1) in-register,
// then W2 GEMV; atomics into out (bias pre-set). Ballot row resolution;
// duplicate central rows each accumulate independently.
__global__ void __launch_bounds__(256) k_l2(P p) {
    __shared__ float w1s[IN_CH * HID_CH];   // 4 KB
    __shared__ float b1s[HID_CH];
    __shared__ float w2s[HID_CH * OUT_CH];  // 32 KB
    __shared__ int cent[128];
    for (int t = threadIdx.x; t < IN_CH * HID_CH; t += blockDim.x) w1s[t] = p.W1[t];
    if (threadIdx.x < HID_CH) b1s[threadIdx.x] = p.b1[threadIdx.x];
    for (int t = threadIdx.x; t < HID_CH * OUT_CH; t += blockDim.x) w2s[t] = p.W2[t];
    if (threadIdx.x < 128) cent[threadIdx.x] = p.ptr[threadIdx.x];
    __syncthreads();
    int lane = threadIdx.x & 63;
    int c0 = cent[lane];
    int c1v = cent[lane + 64];
    int wid = blockIdx.x * (blockDim.x >> 6) + (threadIdx.x >> 6);
    int nw = gridDim.x * (blockDim.x >> 6);
    int n2 = min(p.cnt[2], CAP2);
    for (int w = wid; w < n2 + N_GRAPHS; w += nw) {
        int s, d, selfrow = -1;
        if (w < n2) {
            int e = p.list2[w];
            s = p.src[e]; d = p.dst[e];
        } else {
            selfrow = w - n2;
            s = cent[selfrow]; d = s;
        }
        int slot = p.map1[s]; if (slot < 0) slot = 0;  // always marked
        float dis_s = rsqrtf((float)(1u + p.deg[s]));
        float dis_d = rsqrtf((float)(1u + p.deg[d]));
        float norm = dis_s * dis_d;
        float vc = 0.0f;
        if (lane < IN_CH)
            vc = dis_s * p.agg1[(size_t)slot * IN_CH + lane]
               + dis_s * dis_s * p.x[(size_t)s * IN_CH + lane];
        float h = b1s[lane];
#pragma unroll
        for (int c = 0; c < IN_CH; ++c)
            h += __shfl(vc, c, 64) * w1s[c * HID_CH + lane];
        h = fmaxf(h, 0.0f);
        float a0 = 0.0f, a1 = 0.0f;
#pragma unroll 8
        for (int j = 0; j < HID_CH; ++j) {
            float hv = __shfl(h, j, 64);
            a0 += hv * w2s[j * OUT_CH + lane];
            a1 += hv * w2s[j * OUT_CH + lane + 64];
        }
        a0 *= norm; a1 *= norm;
        if (selfrow >= 0) {
            atomicAdd(&p.out[selfrow * OUT_CH + lane], a0);
            atomicAdd(&p.out[selfrow * OUT_CH + lane + 64], a1);
        } else {
            unsigned long long b0 = __ballot(c0 == d);
            unsigned long long b1 = __ballot(c1v == d);
            while (b0) {
                int r = __ffsll((long long)b0) - 1; b0 &= b0 - 1;
                atomicAdd(&p.out[r * OUT_CH + lane], a0);
                atomicAdd(&p.out[r * OUT_CH + lane + 64], a1);
            }
            while (b1) {
                int r = __ffsll((long long)b1) - 1 + 64; b1 &= b1 - 1;
                atomicAdd(&p.out[r * OUT_CH + lane], a0);
                atomicAdd(&p.out[r * OUT_CH + lane + 64], a1);
            }
        }
    }
}

// ---------------- launch ----------------

extern "C" void kernel_launch(void* const* d_in, const int* in_sizes, int n_in,
                              void* d_out, int out_size, void* d_ws, size_t ws_size,
                              hipStream_t stream) {
    P p;
    p.x   = (const float*)d_in[0];          // fp32 (validated)
    const int* edge = (const int*)d_in[1];  // int32 (validated)
    p.src = edge;
    p.dst = edge + N_EDGES;
    p.ptr = (const int*)d_in[2];
    p.W1  = (const float*)d_in[3];
    p.b1  = (const float*)d_in[4];
    p.W2  = (const float*)d_in[5];
    p.b2  = (const float*)d_in[6];
    p.out = (float*)d_out;

    char* q = (char*)d_ws;
    auto alloc = [&](size_t bytes) {
        char* r = q; q += (bytes + 255) & ~size_t(255); return r;
    };
    p.deg      = (unsigned*)alloc((size_t)N_NODES * 4);
    p.map1     = (int*)     alloc((size_t)N_NODES * 4);
    p.slotnode = (int*)     alloc((size_t)CAPS * 4);
    p.list1    = (int*)     alloc((size_t)CAP1 * 4);
    p.list2    = (int*)     alloc((size_t)CAP2 * 4);
    p.agg1     = (float*)   alloc((size_t)CAPS * IN_CH * 4);
    p.markbm   = (unsigned*)alloc((size_t)BM_PAD * 4);
    p.ndbm     = (unsigned*)alloc((size_t)BM_PAD * 4);
    p.cnt      = (int*)     alloc(256);

    hipLaunchKernelGGL(k_prep, dim3(8),    dim3(256), 0, stream, p);
    hipLaunchKernelGGL(k_p1,   dim3(NBLK), dim3(256), 0, stream, p);
    hipLaunchKernelGGL(k_np2,  dim3(NBLK), dim3(256), 0, stream, p);
    hipLaunchKernelGGL(k_p3,   dim3(NBLK), dim3(256), 0, stream, p);
    hipLaunchKernelGGL(k_l1a,  dim3(NBLK), dim3(256), 0, stream, p);
    hipLaunchKernelGGL(k_l2,   dim3(128),  dim3(256), 0, stream, p);
}